// Round 6
// baseline (366.875 us; speedup 1.0000x reference)
//
#include <hip/hip_runtime.h>
#include <math.h>

#define NNODES (128*2048)
#define NEDGES (NNODES*8)
#define NPG 2048
#define EPG (NPG*8)
#define NGRAPH 128
#define KSEL1 1639
#define KSEL2 1312

// ---------- per-graph CSR build: hist + scan + place, one 1024-thread WG ----------
__global__ __launch_bounds__(1024) void k_csr(
    const int* __restrict__ src, const int* __restrict__ dst,
    const float* __restrict__ ew, int* __restrict__ offsets,
    int* __restrict__ counts, int2* __restrict__ edge_sorted)
{
    __shared__ int cnt[NPG];
    __shared__ int curs[NPG];
    __shared__ int wsum[1024];
    int t = threadIdx.x;
    int g = blockIdx.x;
    const int ebase = g * EPG;
    for (int i = t; i < NPG; i += 1024) cnt[i] = 0;
    __syncthreads();
    for (int i = t; i < EPG; i += 1024)
        atomicAdd(&cnt[dst[ebase + i] & (NPG-1)], 1);
    __syncthreads();
    int base = t * 2;
    int l0 = cnt[base], l1 = cnt[base+1];
    int s0 = l0 + l1;
    wsum[t] = s0;
    __syncthreads();
    for (int off=1; off<1024; off<<=1) {
        int add = (t>=off)?wsum[t-off]:0;
        __syncthreads();
        wsum[t]+=add;
        __syncthreads();
    }
    int run = wsum[t]-s0;
    curs[base] = run; curs[base+1] = run + l0;
    __syncthreads();
    for (int i = t; i < NPG; i += 1024) {
        offsets[g*NPG + i] = ebase + curs[i];
        counts[g*NPG + i]  = cnt[i];
    }
    __syncthreads();
    for (int i = t; i < EPG; i += 1024) {
        int d = dst[ebase + i] & (NPG-1);
        int pos = atomicAdd(&curs[d], 1);
        edge_sorted[ebase + pos] = make_int2(src[ebase+i], __float_as_int(ew[ebase+i]));
    }
}

// ---------- conv1 front-end: 8x8 register tiling ----------
// thread t: q = t>>5 (0..7), ng = t&31; nodes nb..nb+7, outputs q*8..q*8+7 of
// concat[y(32) | seed(32)];  y = x@Wrel, seed = x@Wroot + b.
__global__ __launch_bounds__(256) void k_gemm64(
    const float* __restrict__ x, const float* __restrict__ Wrel,
    const float* __restrict__ Wroot, const float* __restrict__ b,
    float* __restrict__ y, float* __restrict__ seed)
{
    __shared__ float wcat[64*64];   // wcat[k][j]: j<32 Wrel, j>=32 Wroot
    __shared__ float bb[32];
    int t = threadIdx.x;
    for (int i = t; i < 64*64; i += 256) {
        int k = i >> 6, j = i & 63;
        wcat[i] = (j < 32) ? Wrel[k*32 + j] : Wroot[k*32 + (j-32)];
    }
    if (t < 32) bb[t] = b[t];
    __syncthreads();
    int q = t >> 5, ng = t & 31;
    size_t nb = (size_t)blockIdx.x * 256 + (size_t)ng * 8;
    const float* xb = x + nb * 64;
    float acc[8][8];
    #pragma unroll
    for (int i=0;i<8;++i)
        #pragma unroll
        for (int j=0;j<8;++j) acc[i][j]=0.f;
    for (int k = 0; k < 64; k += 4) {
        float4 xs[8];
        #pragma unroll
        for (int i=0;i<8;++i) xs[i] = *(const float4*)(xb + i*64 + k);
        float4 w0[4], w1[4];
        #pragma unroll
        for (int kk=0;kk<4;++kk) {
            w0[kk] = *(const float4*)(&wcat[(k+kk)*64 + q*8]);
            w1[kk] = *(const float4*)(&wcat[(k+kk)*64 + q*8 + 4]);
        }
        #pragma unroll
        for (int i=0;i<8;++i) {
            float xv[4] = {xs[i].x, xs[i].y, xs[i].z, xs[i].w};
            #pragma unroll
            for (int kk=0;kk<4;++kk) {
                acc[i][0]=fmaf(xv[kk], w0[kk].x, acc[i][0]);
                acc[i][1]=fmaf(xv[kk], w0[kk].y, acc[i][1]);
                acc[i][2]=fmaf(xv[kk], w0[kk].z, acc[i][2]);
                acc[i][3]=fmaf(xv[kk], w0[kk].w, acc[i][3]);
                acc[i][4]=fmaf(xv[kk], w1[kk].x, acc[i][4]);
                acc[i][5]=fmaf(xv[kk], w1[kk].y, acc[i][5]);
                acc[i][6]=fmaf(xv[kk], w1[kk].z, acc[i][6]);
                acc[i][7]=fmaf(xv[kk], w1[kk].w, acc[i][7]);
            }
        }
    }
    if (q < 4) {               // wave-uniform branch (q = t>>5)
        #pragma unroll
        for (int i=0;i<8;++i) {
            float* yr = y + (nb+i)*32 + q*8;
            *(float4*)yr     = make_float4(acc[i][0],acc[i][1],acc[i][2],acc[i][3]);
            *(float4*)(yr+4) = make_float4(acc[i][4],acc[i][5],acc[i][6],acc[i][7]);
        }
    } else {
        int qq = q - 4;
        float b0=bb[qq*8+0],b1=bb[qq*8+1],b2=bb[qq*8+2],b3=bb[qq*8+3];
        float b4=bb[qq*8+4],b5=bb[qq*8+5],b6=bb[qq*8+6],b7=bb[qq*8+7];
        #pragma unroll
        for (int i=0;i<8;++i) {
            float* sr = seed + (nb+i)*32 + qq*8;
            *(float4*)sr     = make_float4(acc[i][0]+b0,acc[i][1]+b1,acc[i][2]+b2,acc[i][3]+b3);
            *(float4*)(sr+4) = make_float4(acc[i][4]+b4,acc[i][5]+b5,acc[i][6]+b6,acc[i][7]+b7);
        }
    }
}

// ---------- conv2 front-end: 8x8 tiling, hp = h*ts folded as ts*(h@W) ----------
__global__ __launch_bounds__(256) void k_gemm32(
    const float* __restrict__ h, const float* __restrict__ ts,
    const float* __restrict__ Wrel, const float* __restrict__ Wroot,
    const float* __restrict__ b, float* __restrict__ y,
    float* __restrict__ seed)
{
    __shared__ float wcat[32*64];
    __shared__ float bb[32];
    int t = threadIdx.x;
    for (int i = t; i < 32*64; i += 256) {
        int k = i >> 6, j = i & 63;
        wcat[i] = (j < 32) ? Wrel[k*32 + j] : Wroot[k*32 + (j-32)];
    }
    if (t < 32) bb[t] = b[t];
    __syncthreads();
    int q = t >> 5, ng = t & 31;
    size_t nb = (size_t)blockIdx.x * 256 + (size_t)ng * 8;
    const float* hb = h + nb * 32;
    float tsv[8];
    #pragma unroll
    for (int i=0;i<8;++i) tsv[i] = ts[nb+i];
    float acc[8][8];
    #pragma unroll
    for (int i=0;i<8;++i)
        #pragma unroll
        for (int j=0;j<8;++j) acc[i][j]=0.f;
    for (int k = 0; k < 32; k += 4) {
        float4 xs[8];
        #pragma unroll
        for (int i=0;i<8;++i) xs[i] = *(const float4*)(hb + i*32 + k);
        float4 w0[4], w1[4];
        #pragma unroll
        for (int kk=0;kk<4;++kk) {
            w0[kk] = *(const float4*)(&wcat[(k+kk)*64 + q*8]);
            w1[kk] = *(const float4*)(&wcat[(k+kk)*64 + q*8 + 4]);
        }
        #pragma unroll
        for (int i=0;i<8;++i) {
            float xv[4] = {xs[i].x, xs[i].y, xs[i].z, xs[i].w};
            #pragma unroll
            for (int kk=0;kk<4;++kk) {
                acc[i][0]=fmaf(xv[kk], w0[kk].x, acc[i][0]);
                acc[i][1]=fmaf(xv[kk], w0[kk].y, acc[i][1]);
                acc[i][2]=fmaf(xv[kk], w0[kk].z, acc[i][2]);
                acc[i][3]=fmaf(xv[kk], w0[kk].w, acc[i][3]);
                acc[i][4]=fmaf(xv[kk], w1[kk].x, acc[i][4]);
                acc[i][5]=fmaf(xv[kk], w1[kk].y, acc[i][5]);
                acc[i][6]=fmaf(xv[kk], w1[kk].z, acc[i][6]);
                acc[i][7]=fmaf(xv[kk], w1[kk].w, acc[i][7]);
            }
        }
    }
    if (q < 4) {
        #pragma unroll
        for (int i=0;i<8;++i) {
            float sc = tsv[i];
            float* yr = y + (nb+i)*32 + q*8;
            *(float4*)yr     = make_float4(acc[i][0]*sc,acc[i][1]*sc,acc[i][2]*sc,acc[i][3]*sc);
            *(float4*)(yr+4) = make_float4(acc[i][4]*sc,acc[i][5]*sc,acc[i][6]*sc,acc[i][7]*sc);
        }
    } else {
        int qq = q - 4;
        float b0=bb[qq*8+0],b1=bb[qq*8+1],b2=bb[qq*8+2],b3=bb[qq*8+3];
        float b4=bb[qq*8+4],b5=bb[qq*8+5],b6=bb[qq*8+6],b7=bb[qq*8+7];
        #pragma unroll
        for (int i=0;i<8;++i) {
            float sc = tsv[i];
            float* sr = seed + (nb+i)*32 + qq*8;
            *(float4*)sr     = make_float4(acc[i][0]*sc+b0,acc[i][1]*sc+b1,acc[i][2]*sc+b2,acc[i][3]*sc+b3);
            *(float4*)(sr+4) = make_float4(acc[i][4]*sc+b4,acc[i][5]*sc+b5,acc[i][6]*sc+b6,acc[i][7]*sc+b7);
        }
    }
}

// ---------- fused gather + relu + score ----------
// 8 lanes per node. Reads seed from seedbuf, writes h into hout (may alias).
__global__ __launch_bounds__(256) void k_gather(
    const int* __restrict__ offsets, const int* __restrict__ counts,
    const int2* __restrict__ edge_sorted,
    const float* __restrict__ y, const float* __restrict__ pw,
    const int* __restrict__ mask, const float* __restrict__ seedbuf,
    float* __restrict__ hout, float* __restrict__ s)
{
    size_t tid = (size_t)blockIdx.x * 256 + threadIdx.x;
    int node = (int)(tid >> 3);
    int q = (int)(tid & 7);
    float4 wv = ((const float4*)pw)[q];
    float nn = wv.x*wv.x + wv.y*wv.y + wv.z*wv.z + wv.w*wv.w;
    nn += __shfl_xor(nn, 1); nn += __shfl_xor(nn, 2); nn += __shfl_xor(nn, 4);
    float nrm = sqrtf(nn);
    bool valid = mask ? (mask[node] != 0) : true;
    float4 acc = make_float4(0.f, 0.f, 0.f, 0.f);
    if (valid) {
        acc = *(const float4*)(seedbuf + (size_t)node * 32 + (size_t)q * 4);
        int beg = offsets[node];
        int end = beg + counts[node];
        for (int e = beg; e < end; ++e) {
            int2 ed = edge_sorted[e];
            float w = __int_as_float(ed.y);
            float4 v = *(const float4*)(y + (size_t)ed.x * 32 + (size_t)q * 4);
            acc.x = fmaf(v.x, w, acc.x);
            acc.y = fmaf(v.y, w, acc.y);
            acc.z = fmaf(v.z, w, acc.z);
            acc.w = fmaf(v.w, w, acc.w);
        }
    }
    float4 hv;
    hv.x = fmaxf(acc.x, 0.f); hv.y = fmaxf(acc.y, 0.f);
    hv.z = fmaxf(acc.z, 0.f); hv.w = fmaxf(acc.w, 0.f);
    *(float4*)(hout + (size_t)node * 32 + (size_t)q * 4) = hv;
    float dot = hv.x*wv.x + hv.y*wv.y + hv.z*wv.z + hv.w*wv.w;
    dot += __shfl_xor(dot, 1); dot += __shfl_xor(dot, 2); dot += __shfl_xor(dot, 4);
    if (q == 0) s[node] = valid ? (dot / nrm) : -INFINITY;
}

// ---------- pooling ----------
__global__ __launch_bounds__(256) void k_pool(
    const float* __restrict__ s, const float* __restrict__ h,
    float* __restrict__ ts_out, int* __restrict__ mask_out,
    float* __restrict__ xout, int ksel)
{
    __shared__ unsigned keys[NPG];
    __shared__ unsigned hist[256];
    __shared__ unsigned scanb[256];
    __shared__ unsigned char flag[NPG];
    __shared__ unsigned sh_bin, sh_krem;
    __shared__ float red[4*64];
    int t = threadIdx.x;
    int g = blockIdx.x;
    const float* sg = s + (size_t)g * NPG;
    for (int i = t; i < NPG; i += 256) {
        unsigned u = __float_as_uint(sg[i]);
        keys[i] = (u & 0x80000000u) ? ~u : (u | 0x80000000u);
    }
    __syncthreads();
    unsigned prefix = 0u;
    unsigned krem = (unsigned)ksel;
    for (int level = 0; level < 4; ++level) {
        int shift = 24 - 8*level;
        hist[t] = 0u;
        __syncthreads();
        unsigned pmask = level ? (0xFFFFFFFFu << (shift + 8)) : 0u;
        for (int i = t; i < NPG; i += 256) {
            unsigned key = keys[i];
            if ((key & pmask) == prefix)
                atomicAdd(&hist[(key >> shift) & 0xFFu], 1u);
        }
        __syncthreads();
        scanb[t] = hist[255 - t];
        __syncthreads();
        for (int off = 1; off < 256; off <<= 1) {
            unsigned add = (t >= off) ? scanb[t - off] : 0u;
            __syncthreads();
            scanb[t] += add;
            __syncthreads();
        }
        unsigned incl = scanb[t];
        unsigned excl = t ? scanb[t-1] : 0u;
        if (incl >= krem && excl < krem) {
            sh_bin = (unsigned)(255 - t);
            sh_krem = krem - excl;
        }
        __syncthreads();
        prefix |= (sh_bin << shift);
        krem = sh_krem;
        __syncthreads();
    }
    unsigned T = prefix;
    unsigned ties = krem;
    int base = t * 8;
    unsigned ceq = 0;
    #pragma unroll
    for (int i=0;i<8;++i) ceq += (keys[base+i] == T) ? 1u : 0u;
    scanb[t] = ceq;
    __syncthreads();
    for (int off = 1; off < 256; off <<= 1) {
        unsigned add = (t >= off) ? scanb[t - off] : 0u;
        __syncthreads();
        scanb[t] += add;
        __syncthreads();
    }
    unsigned run = scanb[t] - ceq;
    #pragma unroll
    for (int i=0;i<8;++i) {
        unsigned key = keys[base+i];
        unsigned char f;
        if (key > T) f = 1;
        else if (key == T) { f = (run < ties) ? 1 : 0; run++; }
        else f = 0;
        flag[base+i] = f;
    }
    __syncthreads();

    float mx[32], sm[32];
    #pragma unroll
    for (int j=0;j<32;++j){ mx[j]=-INFINITY; sm[j]=0.f; }
    const float* hg = h + (size_t)g * NPG * 32;
    for (int i = t; i < NPG; i += 256) {
        bool sel = flag[i] != 0;
        float tsv = sel ? tanhf(sg[i]) : 0.f;
        const float4* hr = (const float4*)(hg + (size_t)i*32);
        #pragma unroll
        for (int j4=0;j4<8;++j4) {
            float4 hv = hr[j4];
            float4 v = make_float4(hv.x*tsv, hv.y*tsv, hv.z*tsv, hv.w*tsv);
            if (sel) {
                mx[4*j4+0] = fmaxf(mx[4*j4+0], v.x); sm[4*j4+0] += v.x;
                mx[4*j4+1] = fmaxf(mx[4*j4+1], v.y); sm[4*j4+1] += v.y;
                mx[4*j4+2] = fmaxf(mx[4*j4+2], v.z); sm[4*j4+2] += v.z;
                mx[4*j4+3] = fmaxf(mx[4*j4+3], v.w); sm[4*j4+3] += v.w;
            }
        }
        if (ts_out) ts_out[(size_t)g*NPG + i] = tsv;
        if (mask_out) mask_out[(size_t)g*NPG + i] = sel ? 1 : 0;
    }
    #pragma unroll
    for (int j=0;j<32;++j) {
        for (int off=32; off; off>>=1) {
            mx[j] = fmaxf(mx[j], __shfl_xor(mx[j], off));
            sm[j] += __shfl_xor(sm[j], off);
        }
    }
    int wave = t >> 6, lane = t & 63;
    if (lane == 0) {
        #pragma unroll
        for (int j=0;j<32;++j) { red[wave*64 + j] = mx[j]; red[wave*64 + 32 + j] = sm[j]; }
    }
    __syncthreads();
    if (t < 32) {
        float m = red[t], ss = red[32 + t];
        #pragma unroll
        for (int w=1; w<4; ++w) { m = fmaxf(m, red[w*64 + t]); ss += red[w*64 + 32 + t]; }
        xout[(size_t)g*64 + t] = m;
        xout[(size_t)g*64 + 32 + t] = ss / (float)ksel;
    }
}

__global__ __launch_bounds__(128) void k_readout(
    const float* __restrict__ x1, const float* __restrict__ x2,
    const float* __restrict__ l1W, const float* __restrict__ l1b,
    const float* __restrict__ l2W, const float* __restrict__ l2b,
    const float* __restrict__ l3W, const float* __restrict__ l3b,
    float* __restrict__ out)
{
    int g = threadIdx.x;
    float z[64];
    #pragma unroll
    for (int i=0;i<64;++i) z[i] = x1[g*64+i] + x2[g*64+i];
    float a1[32];
    for (int j=0;j<32;++j) {
        float acc = l1b[j];
        #pragma unroll
        for (int i=0;i<64;++i) acc = fmaf(z[i], l1W[i*32+j], acc);
        a1[j] = fmaxf(acc, 0.f);
    }
    float a2[16];
    for (int j=0;j<16;++j) {
        float acc = l2b[j];
        #pragma unroll
        for (int i=0;i<32;++i) acc = fmaf(a1[i], l2W[i*16+j], acc);
        a2[j] = fmaxf(acc, 0.f);
    }
    float o0 = l3b[0], o1 = l3b[1];
    #pragma unroll
    for (int i=0;i<16;++i) { o0 = fmaf(a2[i], l3W[i*2+0], o0); o1 = fmaf(a2[i], l3W[i*2+1], o1); }
    float m = fmaxf(o0, o1);
    float lse = m + logf(expf(o0-m) + expf(o1-m));
    out[g*2+0] = o0 - lse;
    out[g*2+1] = o1 - lse;
}

extern "C" void kernel_launch(void* const* d_in, const int* in_sizes, int n_in,
                              void* d_out, int out_size, void* d_ws, size_t ws_size,
                              hipStream_t stream)
{
    const float* x      = (const float*)d_in[0];
    const int*   ei     = (const int*)d_in[1];   // int32 (JAX x64 disabled)
    const float* eattr  = (const float*)d_in[2];
    const float* W1rel  = (const float*)d_in[4];
    const float* b1     = (const float*)d_in[5];
    const float* W1root = (const float*)d_in[6];
    const float* p1w    = (const float*)d_in[7];
    const float* W2rel  = (const float*)d_in[8];
    const float* b2     = (const float*)d_in[9];
    const float* W2root = (const float*)d_in[10];
    const float* p2w    = (const float*)d_in[11];
    const float* l1W    = (const float*)d_in[12];
    const float* l1b    = (const float*)d_in[13];
    const float* l2W    = (const float*)d_in[14];
    const float* l2b    = (const float*)d_in[15];
    const float* l3W    = (const float*)d_in[16];
    const float* l3b    = (const float*)d_in[17];
    const int* srcp = ei;
    const int* dstp = ei + NEDGES;

    float* ws   = (float*)d_ws;
    float* y    = ws;                                 // [NNODES,32]
    float* aggh = y    + (size_t)NNODES*32;           // [NNODES,32] h
    float* seedb= aggh + (size_t)NNODES*32;           // [NNODES,32] seed
    float* s1   = seedb+ (size_t)NNODES*32;           // [NNODES]
    float* ts   = s1 + NNODES;                        // [NNODES]
    int*   mask = (int*)(ts + NNODES);                // [NNODES]
    float* x1   = (float*)(mask + NNODES);            // [128,64]
    float* x2   = x1 + NGRAPH*64;                     // [128,64]
    int*   counts    = (int*)(x2 + NGRAPH*64);        // [NNODES]
    int*   offsets   = counts + NNODES;               // [NNODES]
    int2*  edge_sorted = (int2*)(offsets + NNODES);   // [NEDGES] (src, ew)
    float* out  = (float*)d_out;

    dim3 b256(256);
    // ---- CSR build: one 1024-thread workgroup per graph ----
    k_csr<<<NGRAPH, dim3(1024), 0, stream>>>(srcp, dstp, eattr, offsets, counts,
                                             edge_sorted);
    // ---- conv1 front-end + gather/score ----
    k_gemm64<<<NNODES/256, b256, 0, stream>>>(x, W1rel, W1root, b1, y, seedb);
    k_gather<<<NNODES*8/256, b256, 0, stream>>>(offsets, counts, edge_sorted,
                                                y, p1w, nullptr, seedb, aggh, s1);
    // ---- pool1 (ts + mask + x1; h untouched) ----
    k_pool<<<NGRAPH, b256, 0, stream>>>(s1, aggh, ts, mask, x1, KSEL1);
    // ---- conv2 front-end (ts fused) + gather/score ----
    k_gemm32<<<NNODES/256, b256, 0, stream>>>(aggh, ts, W2rel, W2root, b2, y, seedb);
    k_gather<<<NNODES*8/256, b256, 0, stream>>>(offsets, counts, edge_sorted,
                                                y, p2w, mask, seedb, aggh, s1);
    // ---- pool2 (x2 only) ----
    k_pool<<<NGRAPH, b256, 0, stream>>>(s1, aggh, nullptr, nullptr, x2, KSEL2);
    // ---- readout MLP ----
    k_readout<<<1, 128, 0, stream>>>(x1, x2, l1W, l1b, l2W, l2b, l3W, l3b, out);
}

// Round 7
// 303.457 us; speedup vs baseline: 1.2090x; 1.2090x over previous
//
#include <hip/hip_runtime.h>
#include <math.h>

#define NNODES (128*2048)
#define NEDGES (NNODES*8)
#define NPG 2048
#define EPG (NPG*8)
#define NGRAPH 128
#define KSEL1 1639
#define KSEL2 1312

// ---------- per-graph CSR build: hist + scan + place, one 1024-thread WG ----------
__global__ __launch_bounds__(1024) void k_csr(
    const int* __restrict__ src, const int* __restrict__ dst,
    const float* __restrict__ ew, int* __restrict__ offsets,
    int* __restrict__ counts, int2* __restrict__ edge_sorted)
{
    __shared__ int cnt[NPG];
    __shared__ int curs[NPG];
    __shared__ int wsum[1024];
    int t = threadIdx.x;
    int g = blockIdx.x;
    const int ebase = g * EPG;
    for (int i = t; i < NPG; i += 1024) cnt[i] = 0;
    __syncthreads();
    for (int i = t; i < EPG; i += 1024)
        atomicAdd(&cnt[dst[ebase + i] & (NPG-1)], 1);
    __syncthreads();
    int base = t * 2;
    int l0 = cnt[base], l1 = cnt[base+1];
    int s0 = l0 + l1;
    wsum[t] = s0;
    __syncthreads();
    for (int off=1; off<1024; off<<=1) {
        int add = (t>=off)?wsum[t-off]:0;
        __syncthreads();
        wsum[t]+=add;
        __syncthreads();
    }
    int run = wsum[t]-s0;
    curs[base] = run; curs[base+1] = run + l0;
    __syncthreads();
    for (int i = t; i < NPG; i += 1024) {
        offsets[g*NPG + i] = ebase + curs[i];
        counts[g*NPG + i]  = cnt[i];
    }
    __syncthreads();
    for (int i = t; i < EPG; i += 1024) {
        int d = dst[ebase + i] & (NPG-1);
        int pos = atomicAdd(&curs[d], 1);
        edge_sorted[ebase + pos] = make_int2(src[ebase+i], __float_as_int(ew[ebase+i]));
    }
}

// ---------- conv1 front-end: LDS-staged x, 4-node x 8-out register tile ----------
// 128 nodes/block. thread t: q = t>>5 (0..7), ng = t&31 -> nodes ng+32i.
// outputs q*8..q*8+7 of concat[y(32) | seed(32)]; y=x@Wrel, seed=x@Wroot+b.
#define XPAD64 68
__global__ __launch_bounds__(256) void k_gemm64(
    const float* __restrict__ x, const float* __restrict__ Wrel,
    const float* __restrict__ Wroot, const float* __restrict__ b,
    float* __restrict__ y, float* __restrict__ seed)
{
    __shared__ float xs[128*XPAD64];   // 34.8 KB, row stride 68 (16B-aligned, bank-skewed)
    __shared__ float wcat[64*64];      // 16 KB: wcat[k][j]: j<32 Wrel, j>=32 Wroot
    __shared__ float bb[32];
    int t = threadIdx.x;
    for (int i = t; i < 64*64; i += 256) {
        int k = i >> 6, j = i & 63;
        wcat[i] = (j < 32) ? Wrel[k*32 + j] : Wroot[k*32 + (j-32)];
    }
    if (t < 32) bb[t] = b[t];
    size_t nb = (size_t)blockIdx.x * 128;
    const float4* xg = (const float4*)(x + nb * 64);
    for (int i = t; i < 128*16; i += 256) {
        int r = i >> 4, c = i & 15;
        *(float4*)(&xs[r*XPAD64 + c*4]) = xg[i];
    }
    __syncthreads();
    int q = t >> 5, ng = t & 31;
    float acc[4][8];
    #pragma unroll
    for (int i=0;i<4;++i)
        #pragma unroll
        for (int j=0;j<8;++j) acc[i][j]=0.f;
    #pragma unroll 4
    for (int k = 0; k < 64; k += 4) {
        float4 w0[4], w1[4];
        #pragma unroll
        for (int kk=0;kk<4;++kk) {
            w0[kk] = *(const float4*)(&wcat[(k+kk)*64 + q*8]);
            w1[kk] = *(const float4*)(&wcat[(k+kk)*64 + q*8 + 4]);
        }
        #pragma unroll
        for (int i=0;i<4;++i) {
            float4 xv = *(const float4*)(&xs[(ng + i*32)*XPAD64 + k]);
            float xvv[4] = {xv.x, xv.y, xv.z, xv.w};
            #pragma unroll
            for (int kk=0;kk<4;++kk) {
                acc[i][0]=fmaf(xvv[kk], w0[kk].x, acc[i][0]);
                acc[i][1]=fmaf(xvv[kk], w0[kk].y, acc[i][1]);
                acc[i][2]=fmaf(xvv[kk], w0[kk].z, acc[i][2]);
                acc[i][3]=fmaf(xvv[kk], w0[kk].w, acc[i][3]);
                acc[i][4]=fmaf(xvv[kk], w1[kk].x, acc[i][4]);
                acc[i][5]=fmaf(xvv[kk], w1[kk].y, acc[i][5]);
                acc[i][6]=fmaf(xvv[kk], w1[kk].z, acc[i][6]);
                acc[i][7]=fmaf(xvv[kk], w1[kk].w, acc[i][7]);
            }
        }
    }
    if (q < 4) {               // wave-uniform branch (q = t>>5)
        #pragma unroll
        for (int i=0;i<4;++i) {
            float* yr = y + (nb + ng + i*32)*32 + q*8;
            *(float4*)yr     = make_float4(acc[i][0],acc[i][1],acc[i][2],acc[i][3]);
            *(float4*)(yr+4) = make_float4(acc[i][4],acc[i][5],acc[i][6],acc[i][7]);
        }
    } else {
        int qq = q - 4;
        float b0=bb[qq*8+0],b1=bb[qq*8+1],b2=bb[qq*8+2],b3=bb[qq*8+3];
        float b4=bb[qq*8+4],b5=bb[qq*8+5],b6=bb[qq*8+6],b7=bb[qq*8+7];
        #pragma unroll
        for (int i=0;i<4;++i) {
            float* sr = seed + (nb + ng + i*32)*32 + qq*8;
            *(float4*)sr     = make_float4(acc[i][0]+b0,acc[i][1]+b1,acc[i][2]+b2,acc[i][3]+b3);
            *(float4*)(sr+4) = make_float4(acc[i][4]+b4,acc[i][5]+b5,acc[i][6]+b6,acc[i][7]+b7);
        }
    }
}

// ---------- conv2 front-end: same structure, K=32, ts folded as ts*(h@W) ----------
#define XPAD32 36
__global__ __launch_bounds__(256) void k_gemm32(
    const float* __restrict__ h, const float* __restrict__ ts,
    const float* __restrict__ Wrel, const float* __restrict__ Wroot,
    const float* __restrict__ b, float* __restrict__ y,
    float* __restrict__ seed)
{
    __shared__ float xs[128*XPAD32];   // 18.4 KB
    __shared__ float wcat[32*64];      // 8 KB
    __shared__ float bb[32];
    int t = threadIdx.x;
    for (int i = t; i < 32*64; i += 256) {
        int k = i >> 6, j = i & 63;
        wcat[i] = (j < 32) ? Wrel[k*32 + j] : Wroot[k*32 + (j-32)];
    }
    if (t < 32) bb[t] = b[t];
    size_t nb = (size_t)blockIdx.x * 128;
    const float4* hg = (const float4*)(h + nb * 32);
    for (int i = t; i < 128*8; i += 256) {
        int r = i >> 3, c = i & 7;
        *(float4*)(&xs[r*XPAD32 + c*4]) = hg[i];
    }
    __syncthreads();
    int q = t >> 5, ng = t & 31;
    float tsv[4];
    #pragma unroll
    for (int i=0;i<4;++i) tsv[i] = ts[nb + ng + i*32];
    float acc[4][8];
    #pragma unroll
    for (int i=0;i<4;++i)
        #pragma unroll
        for (int j=0;j<8;++j) acc[i][j]=0.f;
    #pragma unroll 4
    for (int k = 0; k < 32; k += 4) {
        float4 w0[4], w1[4];
        #pragma unroll
        for (int kk=0;kk<4;++kk) {
            w0[kk] = *(const float4*)(&wcat[(k+kk)*64 + q*8]);
            w1[kk] = *(const float4*)(&wcat[(k+kk)*64 + q*8 + 4]);
        }
        #pragma unroll
        for (int i=0;i<4;++i) {
            float4 xv = *(const float4*)(&xs[(ng + i*32)*XPAD32 + k]);
            float xvv[4] = {xv.x, xv.y, xv.z, xv.w};
            #pragma unroll
            for (int kk=0;kk<4;++kk) {
                acc[i][0]=fmaf(xvv[kk], w0[kk].x, acc[i][0]);
                acc[i][1]=fmaf(xvv[kk], w0[kk].y, acc[i][1]);
                acc[i][2]=fmaf(xvv[kk], w0[kk].z, acc[i][2]);
                acc[i][3]=fmaf(xvv[kk], w0[kk].w, acc[i][3]);
                acc[i][4]=fmaf(xvv[kk], w1[kk].x, acc[i][4]);
                acc[i][5]=fmaf(xvv[kk], w1[kk].y, acc[i][5]);
                acc[i][6]=fmaf(xvv[kk], w1[kk].z, acc[i][6]);
                acc[i][7]=fmaf(xvv[kk], w1[kk].w, acc[i][7]);
            }
        }
    }
    if (q < 4) {
        #pragma unroll
        for (int i=0;i<4;++i) {
            float sc = tsv[i];
            float* yr = y + (nb + ng + i*32)*32 + q*8;
            *(float4*)yr     = make_float4(acc[i][0]*sc,acc[i][1]*sc,acc[i][2]*sc,acc[i][3]*sc);
            *(float4*)(yr+4) = make_float4(acc[i][4]*sc,acc[i][5]*sc,acc[i][6]*sc,acc[i][7]*sc);
        }
    } else {
        int qq = q - 4;
        float b0=bb[qq*8+0],b1=bb[qq*8+1],b2=bb[qq*8+2],b3=bb[qq*8+3];
        float b4=bb[qq*8+4],b5=bb[qq*8+5],b6=bb[qq*8+6],b7=bb[qq*8+7];
        #pragma unroll
        for (int i=0;i<4;++i) {
            float sc = tsv[i];
            float* sr = seed + (nb + ng + i*32)*32 + qq*8;
            *(float4*)sr     = make_float4(acc[i][0]*sc+b0,acc[i][1]*sc+b1,acc[i][2]*sc+b2,acc[i][3]*sc+b3);
            *(float4*)(sr+4) = make_float4(acc[i][4]*sc+b4,acc[i][5]*sc+b5,acc[i][6]*sc+b6,acc[i][7]*sc+b7);
        }
    }
}

// ---------- fused gather + relu + score ----------
// 8 lanes per node. Reads seed from seedbuf, writes h into hout (may alias).
__global__ __launch_bounds__(256) void k_gather(
    const int* __restrict__ offsets, const int* __restrict__ counts,
    const int2* __restrict__ edge_sorted,
    const float* __restrict__ y, const float* __restrict__ pw,
    const int* __restrict__ mask, const float* __restrict__ seedbuf,
    float* __restrict__ hout, float* __restrict__ s)
{
    size_t tid = (size_t)blockIdx.x * 256 + threadIdx.x;
    int node = (int)(tid >> 3);
    int q = (int)(tid & 7);
    float4 wv = ((const float4*)pw)[q];
    float nn = wv.x*wv.x + wv.y*wv.y + wv.z*wv.z + wv.w*wv.w;
    nn += __shfl_xor(nn, 1); nn += __shfl_xor(nn, 2); nn += __shfl_xor(nn, 4);
    float nrm = sqrtf(nn);
    bool valid = mask ? (mask[node] != 0) : true;
    float4 acc = make_float4(0.f, 0.f, 0.f, 0.f);
    if (valid) {
        acc = *(const float4*)(seedbuf + (size_t)node * 32 + (size_t)q * 4);
        int beg = offsets[node];
        int end = beg + counts[node];
        for (int e = beg; e < end; ++e) {
            int2 ed = edge_sorted[e];
            float w = __int_as_float(ed.y);
            float4 v = *(const float4*)(y + (size_t)ed.x * 32 + (size_t)q * 4);
            acc.x = fmaf(v.x, w, acc.x);
            acc.y = fmaf(v.y, w, acc.y);
            acc.z = fmaf(v.z, w, acc.z);
            acc.w = fmaf(v.w, w, acc.w);
        }
    }
    float4 hv;
    hv.x = fmaxf(acc.x, 0.f); hv.y = fmaxf(acc.y, 0.f);
    hv.z = fmaxf(acc.z, 0.f); hv.w = fmaxf(acc.w, 0.f);
    *(float4*)(hout + (size_t)node * 32 + (size_t)q * 4) = hv;
    float dot = hv.x*wv.x + hv.y*wv.y + hv.z*wv.z + hv.w*wv.w;
    dot += __shfl_xor(dot, 1); dot += __shfl_xor(dot, 2); dot += __shfl_xor(dot, 4);
    if (q == 0) s[node] = valid ? (dot / nrm) : -INFINITY;
}

// ---------- pooling ----------
__global__ __launch_bounds__(256) void k_pool(
    const float* __restrict__ s, const float* __restrict__ h,
    float* __restrict__ ts_out, int* __restrict__ mask_out,
    float* __restrict__ xout, int ksel)
{
    __shared__ unsigned keys[NPG];
    __shared__ unsigned hist[256];
    __shared__ unsigned scanb[256];
    __shared__ unsigned char flag[NPG];
    __shared__ unsigned sh_bin, sh_krem;
    __shared__ float red[4*64];
    int t = threadIdx.x;
    int g = blockIdx.x;
    const float* sg = s + (size_t)g * NPG;
    for (int i = t; i < NPG; i += 256) {
        unsigned u = __float_as_uint(sg[i]);
        keys[i] = (u & 0x80000000u) ? ~u : (u | 0x80000000u);
    }
    __syncthreads();
    unsigned prefix = 0u;
    unsigned krem = (unsigned)ksel;
    for (int level = 0; level < 4; ++level) {
        int shift = 24 - 8*level;
        hist[t] = 0u;
        __syncthreads();
        unsigned pmask = level ? (0xFFFFFFFFu << (shift + 8)) : 0u;
        for (int i = t; i < NPG; i += 256) {
            unsigned key = keys[i];
            if ((key & pmask) == prefix)
                atomicAdd(&hist[(key >> shift) & 0xFFu], 1u);
        }
        __syncthreads();
        scanb[t] = hist[255 - t];
        __syncthreads();
        for (int off = 1; off < 256; off <<= 1) {
            unsigned add = (t >= off) ? scanb[t - off] : 0u;
            __syncthreads();
            scanb[t] += add;
            __syncthreads();
        }
        unsigned incl = scanb[t];
        unsigned excl = t ? scanb[t-1] : 0u;
        if (incl >= krem && excl < krem) {
            sh_bin = (unsigned)(255 - t);
            sh_krem = krem - excl;
        }
        __syncthreads();
        prefix |= (sh_bin << shift);
        krem = sh_krem;
        __syncthreads();
    }
    unsigned T = prefix;
    unsigned ties = krem;
    int base = t * 8;
    unsigned ceq = 0;
    #pragma unroll
    for (int i=0;i<8;++i) ceq += (keys[base+i] == T) ? 1u : 0u;
    scanb[t] = ceq;
    __syncthreads();
    for (int off = 1; off < 256; off <<= 1) {
        unsigned add = (t >= off) ? scanb[t - off] : 0u;
        __syncthreads();
        scanb[t] += add;
        __syncthreads();
    }
    unsigned run = scanb[t] - ceq;
    #pragma unroll
    for (int i=0;i<8;++i) {
        unsigned key = keys[base+i];
        unsigned char f;
        if (key > T) f = 1;
        else if (key == T) { f = (run < ties) ? 1 : 0; run++; }
        else f = 0;
        flag[base+i] = f;
    }
    __syncthreads();

    float mx[32], sm[32];
    #pragma unroll
    for (int j=0;j<32;++j){ mx[j]=-INFINITY; sm[j]=0.f; }
    const float* hg = h + (size_t)g * NPG * 32;
    for (int i = t; i < NPG; i += 256) {
        bool sel = flag[i] != 0;
        float tsv = sel ? tanhf(sg[i]) : 0.f;
        const float4* hr = (const float4*)(hg + (size_t)i*32);
        #pragma unroll
        for (int j4=0;j4<8;++j4) {
            float4 hv = hr[j4];
            float4 v = make_float4(hv.x*tsv, hv.y*tsv, hv.z*tsv, hv.w*tsv);
            if (sel) {
                mx[4*j4+0] = fmaxf(mx[4*j4+0], v.x); sm[4*j4+0] += v.x;
                mx[4*j4+1] = fmaxf(mx[4*j4+1], v.y); sm[4*j4+1] += v.y;
                mx[4*j4+2] = fmaxf(mx[4*j4+2], v.z); sm[4*j4+2] += v.z;
                mx[4*j4+3] = fmaxf(mx[4*j4+3], v.w); sm[4*j4+3] += v.w;
            }
        }
        if (ts_out) ts_out[(size_t)g*NPG + i] = tsv;
        if (mask_out) mask_out[(size_t)g*NPG + i] = sel ? 1 : 0;
    }
    #pragma unroll
    for (int j=0;j<32;++j) {
        for (int off=32; off; off>>=1) {
            mx[j] = fmaxf(mx[j], __shfl_xor(mx[j], off));
            sm[j] += __shfl_xor(sm[j], off);
        }
    }
    int wave = t >> 6, lane = t & 63;
    if (lane == 0) {
        #pragma unroll
        for (int j=0;j<32;++j) { red[wave*64 + j] = mx[j]; red[wave*64 + 32 + j] = sm[j]; }
    }
    __syncthreads();
    if (t < 32) {
        float m = red[t], ss = red[32 + t];
        #pragma unroll
        for (int w=1; w<4; ++w) { m = fmaxf(m, red[w*64 + t]); ss += red[w*64 + 32 + t]; }
        xout[(size_t)g*64 + t] = m;
        xout[(size_t)g*64 + 32 + t] = ss / (float)ksel;
    }
}

__global__ __launch_bounds__(128) void k_readout(
    const float* __restrict__ x1, const float* __restrict__ x2,
    const float* __restrict__ l1W, const float* __restrict__ l1b,
    const float* __restrict__ l2W, const float* __restrict__ l2b,
    const float* __restrict__ l3W, const float* __restrict__ l3b,
    float* __restrict__ out)
{
    int g = threadIdx.x;
    float z[64];
    #pragma unroll
    for (int i=0;i<64;++i) z[i] = x1[g*64+i] + x2[g*64+i];
    float a1[32];
    for (int j=0;j<32;++j) {
        float acc = l1b[j];
        #pragma unroll
        for (int i=0;i<64;++i) acc = fmaf(z[i], l1W[i*32+j], acc);
        a1[j] = fmaxf(acc, 0.f);
    }
    float a2[16];
    for (int j=0;j<16;++j) {
        float acc = l2b[j];
        #pragma unroll
        for (int i=0;i<32;++i) acc = fmaf(a1[i], l2W[i*16+j], acc);
        a2[j] = fmaxf(acc, 0.f);
    }
    float o0 = l3b[0], o1 = l3b[1];
    #pragma unroll
    for (int i=0;i<16;++i) { o0 = fmaf(a2[i], l3W[i*2+0], o0); o1 = fmaf(a2[i], l3W[i*2+1], o1); }
    float m = fmaxf(o0, o1);
    float lse = m + logf(expf(o0-m) + expf(o1-m));
    out[g*2+0] = o0 - lse;
    out[g*2+1] = o1 - lse;
}

extern "C" void kernel_launch(void* const* d_in, const int* in_sizes, int n_in,
                              void* d_out, int out_size, void* d_ws, size_t ws_size,
                              hipStream_t stream)
{
    const float* x      = (const float*)d_in[0];
    const int*   ei     = (const int*)d_in[1];   // int32 (JAX x64 disabled)
    const float* eattr  = (const float*)d_in[2];
    const float* W1rel  = (const float*)d_in[4];
    const float* b1     = (const float*)d_in[5];
    const float* W1root = (const float*)d_in[6];
    const float* p1w    = (const float*)d_in[7];
    const float* W2rel  = (const float*)d_in[8];
    const float* b2     = (const float*)d_in[9];
    const float* W2root = (const float*)d_in[10];
    const float* p2w    = (const float*)d_in[11];
    const float* l1W    = (const float*)d_in[12];
    const float* l1b    = (const float*)d_in[13];
    const float* l2W    = (const float*)d_in[14];
    const float* l2b    = (const float*)d_in[15];
    const float* l3W    = (const float*)d_in[16];
    const float* l3b    = (const float*)d_in[17];
    const int* srcp = ei;
    const int* dstp = ei + NEDGES;

    float* ws   = (float*)d_ws;
    float* y    = ws;                                 // [NNODES,32]
    float* aggh = y    + (size_t)NNODES*32;           // [NNODES,32] h
    float* seedb= aggh + (size_t)NNODES*32;           // [NNODES,32] seed
    float* s1   = seedb+ (size_t)NNODES*32;           // [NNODES]
    float* ts   = s1 + NNODES;                        // [NNODES]
    int*   mask = (int*)(ts + NNODES);                // [NNODES]
    float* x1   = (float*)(mask + NNODES);            // [128,64]
    float* x2   = x1 + NGRAPH*64;                     // [128,64]
    int*   counts    = (int*)(x2 + NGRAPH*64);        // [NNODES]
    int*   offsets   = counts + NNODES;               // [NNODES]
    int2*  edge_sorted = (int2*)(offsets + NNODES);   // [NEDGES] (src, ew)
    float* out  = (float*)d_out;

    dim3 b256(256);
    // ---- CSR build: one 1024-thread workgroup per graph ----
    k_csr<<<NGRAPH, dim3(1024), 0, stream>>>(srcp, dstp, eattr, offsets, counts,
                                             edge_sorted);
    // ---- conv1 front-end + gather/score ----
    k_gemm64<<<NNODES/128, b256, 0, stream>>>(x, W1rel, W1root, b1, y, seedb);
    k_gather<<<NNODES*8/256, b256, 0, stream>>>(offsets, counts, edge_sorted,
                                                y, p1w, nullptr, seedb, aggh, s1);
    // ---- pool1 (ts + mask + x1; h untouched) ----
    k_pool<<<NGRAPH, b256, 0, stream>>>(s1, aggh, ts, mask, x1, KSEL1);
    // ---- conv2 front-end (ts fused) + gather/score ----
    k_gemm32<<<NNODES/128, b256, 0, stream>>>(aggh, ts, W2rel, W2root, b2, y, seedb);
    k_gather<<<NNODES*8/256, b256, 0, stream>>>(offsets, counts, edge_sorted,
                                                y, p2w, mask, seedb, aggh, s1);
    // ---- pool2 (x2 only) ----
    k_pool<<<NGRAPH, b256, 0, stream>>>(s1, aggh, nullptr, nullptr, x2, KSEL2);
    // ---- readout MLP ----
    k_readout<<<1, 128, 0, stream>>>(x1, x2, l1W, l1b, l2W, l2b, l3W, l3b, out);
}

// Round 8
// 300.810 us; speedup vs baseline: 1.2196x; 1.0088x over previous
//
#include <hip/hip_runtime.h>
#include <math.h>

#define NNODES (128*2048)
#define NEDGES (NNODES*8)
#define NPG 2048
#define EPG (NPG*8)
#define HPG (EPG/2)          // 8192 edges per partition
#define NGRAPH 128
#define KSEL1 1639
#define KSEL2 1312

// ---------- partitioned CSR build: 2 WGs per graph, register-staged edges ----------
// WG (g,part) owns edges [g*EPG + part*HPG, +HPG) and builds an independent
// dst-sorted segment there. meta[part*NNODES + node] = (start, count).
__global__ __launch_bounds__(1024) void k_csr(
    const int* __restrict__ src, const int* __restrict__ dst,
    const float* __restrict__ ew, int2* __restrict__ meta,
    int2* __restrict__ edge_sorted)
{
    __shared__ int cnt[NPG];
    __shared__ int curs[NPG];
    __shared__ int wsum[1024];
    int t = threadIdx.x;
    int bid = blockIdx.x;
    int g = bid >> 1, part = bid & 1;
    const int ebase = g * EPG + part * HPG;
    int ds[8], ss[8]; float wws[8];
    #pragma unroll
    for (int j=0;j<8;++j) {
        int idx = ebase + t + 1024*j;
        ds[j] = dst[idx] & (NPG-1);
        ss[j] = src[idx];
        wws[j] = ew[idx];
    }
    for (int i = t; i < NPG; i += 1024) cnt[i] = 0;
    __syncthreads();
    #pragma unroll
    for (int j=0;j<8;++j) atomicAdd(&cnt[ds[j]], 1);
    __syncthreads();
    int base = t * 2;
    int l0 = cnt[base], l1 = cnt[base+1];
    int s0 = l0 + l1;
    wsum[t] = s0;
    __syncthreads();
    for (int off=1; off<1024; off<<=1) {
        int add = (t>=off)?wsum[t-off]:0;
        __syncthreads();
        wsum[t]+=add;
        __syncthreads();
    }
    int run = wsum[t]-s0;
    curs[base] = run; curs[base+1] = run + l0;
    __syncthreads();
    for (int i = t; i < NPG; i += 1024)
        meta[(size_t)part*NNODES + g*NPG + i] = make_int2(ebase + curs[i], cnt[i]);
    __syncthreads();
    #pragma unroll
    for (int j=0;j<8;++j) {
        int pos = atomicAdd(&curs[ds[j]], 1);
        edge_sorted[ebase + pos] = make_int2(ss[j], __float_as_int(wws[j]));
    }
}

// ---------- conv1 front-end: LDS-staged x, 4-node x 8-out register tile ----------
#define XPAD64 68
__global__ __launch_bounds__(256) void k_gemm64(
    const float* __restrict__ x, const float* __restrict__ Wrel,
    const float* __restrict__ Wroot, const float* __restrict__ b,
    float* __restrict__ y, float* __restrict__ seed)
{
    __shared__ float xs[128*XPAD64];
    __shared__ float wcat[64*64];
    __shared__ float bb[32];
    int t = threadIdx.x;
    for (int i = t; i < 64*64; i += 256) {
        int k = i >> 6, j = i & 63;
        wcat[i] = (j < 32) ? Wrel[k*32 + j] : Wroot[k*32 + (j-32)];
    }
    if (t < 32) bb[t] = b[t];
    size_t nb = (size_t)blockIdx.x * 128;
    const float4* xg = (const float4*)(x + nb * 64);
    for (int i = t; i < 128*16; i += 256) {
        int r = i >> 4, c = i & 15;
        *(float4*)(&xs[r*XPAD64 + c*4]) = xg[i];
    }
    __syncthreads();
    int q = t >> 5, ng = t & 31;
    float acc[4][8];
    #pragma unroll
    for (int i=0;i<4;++i)
        #pragma unroll
        for (int j=0;j<8;++j) acc[i][j]=0.f;
    #pragma unroll 4
    for (int k = 0; k < 64; k += 4) {
        float4 w0[4], w1[4];
        #pragma unroll
        for (int kk=0;kk<4;++kk) {
            w0[kk] = *(const float4*)(&wcat[(k+kk)*64 + q*8]);
            w1[kk] = *(const float4*)(&wcat[(k+kk)*64 + q*8 + 4]);
        }
        #pragma unroll
        for (int i=0;i<4;++i) {
            float4 xv = *(const float4*)(&xs[(ng + i*32)*XPAD64 + k]);
            float xvv[4] = {xv.x, xv.y, xv.z, xv.w};
            #pragma unroll
            for (int kk=0;kk<4;++kk) {
                acc[i][0]=fmaf(xvv[kk], w0[kk].x, acc[i][0]);
                acc[i][1]=fmaf(xvv[kk], w0[kk].y, acc[i][1]);
                acc[i][2]=fmaf(xvv[kk], w0[kk].z, acc[i][2]);
                acc[i][3]=fmaf(xvv[kk], w0[kk].w, acc[i][3]);
                acc[i][4]=fmaf(xvv[kk], w1[kk].x, acc[i][4]);
                acc[i][5]=fmaf(xvv[kk], w1[kk].y, acc[i][5]);
                acc[i][6]=fmaf(xvv[kk], w1[kk].z, acc[i][6]);
                acc[i][7]=fmaf(xvv[kk], w1[kk].w, acc[i][7]);
            }
        }
    }
    if (q < 4) {
        #pragma unroll
        for (int i=0;i<4;++i) {
            float* yr = y + (nb + ng + i*32)*32 + q*8;
            *(float4*)yr     = make_float4(acc[i][0],acc[i][1],acc[i][2],acc[i][3]);
            *(float4*)(yr+4) = make_float4(acc[i][4],acc[i][5],acc[i][6],acc[i][7]);
        }
    } else {
        int qq = q - 4;
        float b0=bb[qq*8+0],b1=bb[qq*8+1],b2=bb[qq*8+2],b3=bb[qq*8+3];
        float b4=bb[qq*8+4],b5=bb[qq*8+5],b6=bb[qq*8+6],b7=bb[qq*8+7];
        #pragma unroll
        for (int i=0;i<4;++i) {
            float* sr = seed + (nb + ng + i*32)*32 + qq*8;
            *(float4*)sr     = make_float4(acc[i][0]+b0,acc[i][1]+b1,acc[i][2]+b2,acc[i][3]+b3);
            *(float4*)(sr+4) = make_float4(acc[i][4]+b4,acc[i][5]+b5,acc[i][6]+b6,acc[i][7]+b7);
        }
    }
}

// ---------- conv2 front-end: same structure, K=32, ts folded as ts*(h@W) ----------
#define XPAD32 36
__global__ __launch_bounds__(256) void k_gemm32(
    const float* __restrict__ h, const float* __restrict__ ts,
    const float* __restrict__ Wrel, const float* __restrict__ Wroot,
    const float* __restrict__ b, float* __restrict__ y,
    float* __restrict__ seed)
{
    __shared__ float xs[128*XPAD32];
    __shared__ float wcat[32*64];
    __shared__ float bb[32];
    int t = threadIdx.x;
    for (int i = t; i < 32*64; i += 256) {
        int k = i >> 6, j = i & 63;
        wcat[i] = (j < 32) ? Wrel[k*32 + j] : Wroot[k*32 + (j-32)];
    }
    if (t < 32) bb[t] = b[t];
    size_t nb = (size_t)blockIdx.x * 128;
    const float4* hg = (const float4*)(h + nb * 32);
    for (int i = t; i < 128*8; i += 256) {
        int r = i >> 3, c = i & 7;
        *(float4*)(&xs[r*XPAD32 + c*4]) = hg[i];
    }
    __syncthreads();
    int q = t >> 5, ng = t & 31;
    float tsv[4];
    #pragma unroll
    for (int i=0;i<4;++i) tsv[i] = ts[nb + ng + i*32];
    float acc[4][8];
    #pragma unroll
    for (int i=0;i<4;++i)
        #pragma unroll
        for (int j=0;j<8;++j) acc[i][j]=0.f;
    #pragma unroll 4
    for (int k = 0; k < 32; k += 4) {
        float4 w0[4], w1[4];
        #pragma unroll
        for (int kk=0;kk<4;++kk) {
            w0[kk] = *(const float4*)(&wcat[(k+kk)*64 + q*8]);
            w1[kk] = *(const float4*)(&wcat[(k+kk)*64 + q*8 + 4]);
        }
        #pragma unroll
        for (int i=0;i<4;++i) {
            float4 xv = *(const float4*)(&xs[(ng + i*32)*XPAD32 + k]);
            float xvv[4] = {xv.x, xv.y, xv.z, xv.w};
            #pragma unroll
            for (int kk=0;kk<4;++kk) {
                acc[i][0]=fmaf(xvv[kk], w0[kk].x, acc[i][0]);
                acc[i][1]=fmaf(xvv[kk], w0[kk].y, acc[i][1]);
                acc[i][2]=fmaf(xvv[kk], w0[kk].z, acc[i][2]);
                acc[i][3]=fmaf(xvv[kk], w0[kk].w, acc[i][3]);
                acc[i][4]=fmaf(xvv[kk], w1[kk].x, acc[i][4]);
                acc[i][5]=fmaf(xvv[kk], w1[kk].y, acc[i][5]);
                acc[i][6]=fmaf(xvv[kk], w1[kk].z, acc[i][6]);
                acc[i][7]=fmaf(xvv[kk], w1[kk].w, acc[i][7]);
            }
        }
    }
    if (q < 4) {
        #pragma unroll
        for (int i=0;i<4;++i) {
            float sc = tsv[i];
            float* yr = y + (nb + ng + i*32)*32 + q*8;
            *(float4*)yr     = make_float4(acc[i][0]*sc,acc[i][1]*sc,acc[i][2]*sc,acc[i][3]*sc);
            *(float4*)(yr+4) = make_float4(acc[i][4]*sc,acc[i][5]*sc,acc[i][6]*sc,acc[i][7]*sc);
        }
    } else {
        int qq = q - 4;
        float b0=bb[qq*8+0],b1=bb[qq*8+1],b2=bb[qq*8+2],b3=bb[qq*8+3];
        float b4=bb[qq*8+4],b5=bb[qq*8+5],b6=bb[qq*8+6],b7=bb[qq*8+7];
        #pragma unroll
        for (int i=0;i<4;++i) {
            float sc = tsv[i];
            float* sr = seed + (nb + ng + i*32)*32 + qq*8;
            *(float4*)sr     = make_float4(acc[i][0]*sc+b0,acc[i][1]*sc+b1,acc[i][2]*sc+b2,acc[i][3]*sc+b3);
            *(float4*)(sr+4) = make_float4(acc[i][4]*sc+b4,acc[i][5]*sc+b5,acc[i][6]*sc+b6,acc[i][7]*sc+b7);
        }
    }
}

// ---------- fused gather + relu + score (walks 2 CSR segments) ----------
__global__ __launch_bounds__(256) void k_gather(
    const int2* __restrict__ meta, const int2* __restrict__ edge_sorted,
    const float* __restrict__ y, const float* __restrict__ pw,
    const int* __restrict__ mask, const float* __restrict__ seedbuf,
    float* __restrict__ hout, float* __restrict__ s)
{
    size_t tid = (size_t)blockIdx.x * 256 + threadIdx.x;
    int node = (int)(tid >> 3);
    int q = (int)(tid & 7);
    float4 wv = ((const float4*)pw)[q];
    float nn = wv.x*wv.x + wv.y*wv.y + wv.z*wv.z + wv.w*wv.w;
    nn += __shfl_xor(nn, 1); nn += __shfl_xor(nn, 2); nn += __shfl_xor(nn, 4);
    float nrm = sqrtf(nn);
    bool valid = mask ? (mask[node] != 0) : true;
    float4 acc = make_float4(0.f, 0.f, 0.f, 0.f);
    if (valid) {
        acc = *(const float4*)(seedbuf + (size_t)node * 32 + (size_t)q * 4);
        #pragma unroll
        for (int p = 0; p < 2; ++p) {
            int2 m = meta[(size_t)p*NNODES + node];
            int end = m.x + m.y;
            for (int e = m.x; e < end; ++e) {
                int2 ed = edge_sorted[e];
                float w = __int_as_float(ed.y);
                float4 v = *(const float4*)(y + (size_t)ed.x * 32 + (size_t)q * 4);
                acc.x = fmaf(v.x, w, acc.x);
                acc.y = fmaf(v.y, w, acc.y);
                acc.z = fmaf(v.z, w, acc.z);
                acc.w = fmaf(v.w, w, acc.w);
            }
        }
    }
    float4 hv;
    hv.x = fmaxf(acc.x, 0.f); hv.y = fmaxf(acc.y, 0.f);
    hv.z = fmaxf(acc.z, 0.f); hv.w = fmaxf(acc.w, 0.f);
    *(float4*)(hout + (size_t)node * 32 + (size_t)q * 4) = hv;
    float dot = hv.x*wv.x + hv.y*wv.y + hv.z*wv.z + hv.w*wv.w;
    dot += __shfl_xor(dot, 1); dot += __shfl_xor(dot, 2); dot += __shfl_xor(dot, 4);
    if (q == 0) s[node] = valid ? (dot / nrm) : -INFINITY;
}

// ---------- pooling: 1024-thread radix select + reduce ----------
__global__ __launch_bounds__(1024) void k_pool(
    const float* __restrict__ s, const float* __restrict__ h,
    float* __restrict__ ts_out, int* __restrict__ mask_out,
    float* __restrict__ xout, int ksel)
{
    __shared__ unsigned keys[NPG];
    __shared__ unsigned hist[256];
    __shared__ unsigned scanb[256];
    __shared__ unsigned tiescan[1024];
    __shared__ unsigned char flag[NPG];
    __shared__ unsigned sh_bin, sh_krem;
    __shared__ float red[16*64];
    int t = threadIdx.x;
    int g = blockIdx.x;
    const float* sg = s + (size_t)g * NPG;
    for (int i = t; i < NPG; i += 1024) {
        unsigned u = __float_as_uint(sg[i]);
        keys[i] = (u & 0x80000000u) ? ~u : (u | 0x80000000u);
    }
    __syncthreads();
    unsigned prefix = 0u;
    unsigned krem = (unsigned)ksel;
    for (int level = 0; level < 4; ++level) {
        int shift = 24 - 8*level;
        if (t < 256) hist[t] = 0u;
        __syncthreads();
        unsigned pmask = level ? (0xFFFFFFFFu << (shift + 8)) : 0u;
        for (int i = t; i < NPG; i += 1024) {
            unsigned key = keys[i];
            if ((key & pmask) == prefix)
                atomicAdd(&hist[(key >> shift) & 0xFFu], 1u);
        }
        __syncthreads();
        if (t < 256) scanb[t] = hist[255 - t];
        __syncthreads();
        for (int off = 1; off < 256; off <<= 1) {
            unsigned add = (t < 256 && t >= off) ? scanb[t - off] : 0u;
            __syncthreads();
            if (t < 256) scanb[t] += add;
            __syncthreads();
        }
        if (t < 256) {
            unsigned incl = scanb[t];
            unsigned excl = t ? scanb[t-1] : 0u;
            if (incl >= krem && excl < krem) {
                sh_bin = (unsigned)(255 - t);
                sh_krem = krem - excl;
            }
        }
        __syncthreads();
        prefix |= (sh_bin << shift);
        krem = sh_krem;
        __syncthreads();
    }
    unsigned T = prefix;
    unsigned ties = krem;
    // stable tie selection in index order: thread t owns keys[2t], keys[2t+1]
    int base = t * 2;
    unsigned k0 = keys[base], k1 = keys[base+1];
    unsigned ceq = (k0 == T ? 1u : 0u) + (k1 == T ? 1u : 0u);
    tiescan[t] = ceq;
    __syncthreads();
    for (int off = 1; off < 1024; off <<= 1) {
        unsigned add = (t >= off) ? tiescan[t - off] : 0u;
        __syncthreads();
        tiescan[t] += add;
        __syncthreads();
    }
    unsigned run = tiescan[t] - ceq;
    {
        unsigned char f0, f1;
        if (k0 > T) f0 = 1;
        else if (k0 == T) { f0 = (run < ties) ? 1 : 0; run++; }
        else f0 = 0;
        if (k1 > T) f1 = 1;
        else if (k1 == T) { f1 = (run < ties) ? 1 : 0; run++; }
        else f1 = 0;
        flag[base] = f0; flag[base+1] = f1;
    }
    __syncthreads();

    float mx[32], sm[32];
    #pragma unroll
    for (int j=0;j<32;++j){ mx[j]=-INFINITY; sm[j]=0.f; }
    const float* hg = h + (size_t)g * NPG * 32;
    for (int i = t; i < NPG; i += 1024) {
        bool sel = flag[i] != 0;
        float tsv = sel ? tanhf(sg[i]) : 0.f;
        const float4* hr = (const float4*)(hg + (size_t)i*32);
        #pragma unroll
        for (int j4=0;j4<8;++j4) {
            float4 hv = hr[j4];
            float4 v = make_float4(hv.x*tsv, hv.y*tsv, hv.z*tsv, hv.w*tsv);
            if (sel) {
                mx[4*j4+0] = fmaxf(mx[4*j4+0], v.x); sm[4*j4+0] += v.x;
                mx[4*j4+1] = fmaxf(mx[4*j4+1], v.y); sm[4*j4+1] += v.y;
                mx[4*j4+2] = fmaxf(mx[4*j4+2], v.z); sm[4*j4+2] += v.z;
                mx[4*j4+3] = fmaxf(mx[4*j4+3], v.w); sm[4*j4+3] += v.w;
            }
        }
        if (ts_out) ts_out[(size_t)g*NPG + i] = tsv;
        if (mask_out) mask_out[(size_t)g*NPG + i] = sel ? 1 : 0;
    }
    #pragma unroll
    for (int j=0;j<32;++j) {
        for (int off=32; off; off>>=1) {
            mx[j] = fmaxf(mx[j], __shfl_xor(mx[j], off));
            sm[j] += __shfl_xor(sm[j], off);
        }
    }
    int wave = t >> 6, lane = t & 63;
    if (lane == 0) {
        #pragma unroll
        for (int j=0;j<32;++j) { red[wave*64 + j] = mx[j]; red[wave*64 + 32 + j] = sm[j]; }
    }
    __syncthreads();
    if (t < 32) {
        float m = red[t], ss = red[32 + t];
        #pragma unroll
        for (int w=1; w<16; ++w) { m = fmaxf(m, red[w*64 + t]); ss += red[w*64 + 32 + t]; }
        xout[(size_t)g*64 + t] = m;
        xout[(size_t)g*64 + 32 + t] = ss / (float)ksel;
    }
}

__global__ __launch_bounds__(128) void k_readout(
    const float* __restrict__ x1, const float* __restrict__ x2,
    const float* __restrict__ l1W, const float* __restrict__ l1b,
    const float* __restrict__ l2W, const float* __restrict__ l2b,
    const float* __restrict__ l3W, const float* __restrict__ l3b,
    float* __restrict__ out)
{
    int g = threadIdx.x;
    float z[64];
    #pragma unroll
    for (int i=0;i<64;++i) z[i] = x1[g*64+i] + x2[g*64+i];
    float a1[32];
    for (int j=0;j<32;++j) {
        float acc = l1b[j];
        #pragma unroll
        for (int i=0;i<64;++i) acc = fmaf(z[i], l1W[i*32+j], acc);
        a1[j] = fmaxf(acc, 0.f);
    }
    float a2[16];
    for (int j=0;j<16;++j) {
        float acc = l2b[j];
        #pragma unroll
        for (int i=0;i<32;++i) acc = fmaf(a1[i], l2W[i*16+j], acc);
        a2[j] = fmaxf(acc, 0.f);
    }
    float o0 = l3b[0], o1 = l3b[1];
    #pragma unroll
    for (int i=0;i<16;++i) { o0 = fmaf(a2[i], l3W[i*2+0], o0); o1 = fmaf(a2[i], l3W[i*2+1], o1); }
    float m = fmaxf(o0, o1);
    float lse = m + logf(expf(o0-m) + expf(o1-m));
    out[g*2+0] = o0 - lse;
    out[g*2+1] = o1 - lse;
}

extern "C" void kernel_launch(void* const* d_in, const int* in_sizes, int n_in,
                              void* d_out, int out_size, void* d_ws, size_t ws_size,
                              hipStream_t stream)
{
    const float* x      = (const float*)d_in[0];
    const int*   ei     = (const int*)d_in[1];   // int32 (JAX x64 disabled)
    const float* eattr  = (const float*)d_in[2];
    const float* W1rel  = (const float*)d_in[4];
    const float* b1     = (const float*)d_in[5];
    const float* W1root = (const float*)d_in[6];
    const float* p1w    = (const float*)d_in[7];
    const float* W2rel  = (const float*)d_in[8];
    const float* b2     = (const float*)d_in[9];
    const float* W2root = (const float*)d_in[10];
    const float* p2w    = (const float*)d_in[11];
    const float* l1W    = (const float*)d_in[12];
    const float* l1b    = (const float*)d_in[13];
    const float* l2W    = (const float*)d_in[14];
    const float* l2b    = (const float*)d_in[15];
    const float* l3W    = (const float*)d_in[16];
    const float* l3b    = (const float*)d_in[17];
    const int* srcp = ei;
    const int* dstp = ei + NEDGES;

    float* ws   = (float*)d_ws;
    float* y    = ws;                                 // [NNODES,32]
    float* aggh = y    + (size_t)NNODES*32;           // [NNODES,32] h
    float* seedb= aggh + (size_t)NNODES*32;           // [NNODES,32] seed
    float* s1   = seedb+ (size_t)NNODES*32;           // [NNODES]
    float* ts   = s1 + NNODES;                        // [NNODES]
    int*   mask = (int*)(ts + NNODES);                // [NNODES]
    float* x1   = (float*)(mask + NNODES);            // [128,64]
    float* x2   = x1 + NGRAPH*64;                     // [128,64]
    int2*  meta = (int2*)(x2 + NGRAPH*64);            // [2*NNODES] (start,count)
    int2*  edge_sorted = (int2*)(meta + 2*NNODES);    // [NEDGES] (src, ew)
    float* out  = (float*)d_out;

    dim3 b256(256);
    // ---- partitioned CSR: 2 WGs per graph ----
    k_csr<<<NGRAPH*2, dim3(1024), 0, stream>>>(srcp, dstp, eattr, meta,
                                               edge_sorted);
    // ---- conv1 front-end + gather/score ----
    k_gemm64<<<NNODES/128, b256, 0, stream>>>(x, W1rel, W1root, b1, y, seedb);
    k_gather<<<NNODES*8/256, b256, 0, stream>>>(meta, edge_sorted,
                                                y, p1w, nullptr, seedb, aggh, s1);
    // ---- pool1 (ts + mask + x1; h untouched) ----
    k_pool<<<NGRAPH, dim3(1024), 0, stream>>>(s1, aggh, ts, mask, x1, KSEL1);
    // ---- conv2 front-end (ts fused) + gather/score ----
    k_gemm32<<<NNODES/128, b256, 0, stream>>>(aggh, ts, W2rel, W2root, b2, y, seedb);
    k_gather<<<NNODES*8/256, b256, 0, stream>>>(meta, edge_sorted,
                                                y, p2w, mask, seedb, aggh, s1);
    // ---- pool2 (x2 only) ----
    k_pool<<<NGRAPH, dim3(1024), 0, stream>>>(s1, aggh, nullptr, nullptr, x2, KSEL2);
    // ---- readout MLP ----
    k_readout<<<1, 128, 0, stream>>>(x1, x2, l1W, l1b, l2W, l2b, l3W, l3b, out);
}

// Round 9
// 282.664 us; speedup vs baseline: 1.2979x; 1.0642x over previous
//
#include <hip/hip_runtime.h>
#include <math.h>

#define NNODES (128*2048)
#define NEDGES (NNODES*8)
#define NPG 2048
#define EPG (NPG*8)
#define HPG (EPG/2)          // 8192 edges per partition
#define NGRAPH 128
#define KSEL1 1639
#define KSEL2 1312

// ---------- partitioned CSR build: 2 WGs per graph, register-staged edges ----------
__global__ __launch_bounds__(1024) void k_csr(
    const int* __restrict__ src, const int* __restrict__ dst,
    const float* __restrict__ ew, int2* __restrict__ meta,
    int2* __restrict__ edge_sorted)
{
    __shared__ int cnt[NPG];
    __shared__ int curs[NPG];
    __shared__ int wsum[1024];
    int t = threadIdx.x;
    int bid = blockIdx.x;
    int g = bid >> 1, part = bid & 1;
    const int ebase = g * EPG + part * HPG;
    int ds[8], ss[8]; float wws[8];
    #pragma unroll
    for (int j=0;j<8;++j) {
        int idx = ebase + t + 1024*j;
        ds[j] = dst[idx] & (NPG-1);
        ss[j] = src[idx];
        wws[j] = ew[idx];
    }
    for (int i = t; i < NPG; i += 1024) cnt[i] = 0;
    __syncthreads();
    #pragma unroll
    for (int j=0;j<8;++j) atomicAdd(&cnt[ds[j]], 1);
    __syncthreads();
    int base = t * 2;
    int l0 = cnt[base], l1 = cnt[base+1];
    int s0 = l0 + l1;
    wsum[t] = s0;
    __syncthreads();
    for (int off=1; off<1024; off<<=1) {
        int add = (t>=off)?wsum[t-off]:0;
        __syncthreads();
        wsum[t]+=add;
        __syncthreads();
    }
    int run = wsum[t]-s0;
    curs[base] = run; curs[base+1] = run + l0;
    __syncthreads();
    for (int i = t; i < NPG; i += 1024)
        meta[(size_t)part*NNODES + g*NPG + i] = make_int2(ebase + curs[i], cnt[i]);
    __syncthreads();
    #pragma unroll
    for (int j=0;j<8;++j) {
        int pos = atomicAdd(&curs[ds[j]], 1);
        edge_sorted[ebase + pos] = make_int2(ss[j], __float_as_int(wws[j]));
    }
}

// ---------- conv1 front-end: LDS-staged x, 4-node x 8-out register tile ----------
#define XPAD64 68
__global__ __launch_bounds__(256) void k_gemm64(
    const float* __restrict__ x, const float* __restrict__ Wrel,
    const float* __restrict__ Wroot, const float* __restrict__ b,
    float* __restrict__ y, float* __restrict__ seed)
{
    __shared__ float xs[128*XPAD64];
    __shared__ float wcat[64*64];
    __shared__ float bb[32];
    int t = threadIdx.x;
    for (int i = t; i < 64*64; i += 256) {
        int k = i >> 6, j = i & 63;
        wcat[i] = (j < 32) ? Wrel[k*32 + j] : Wroot[k*32 + (j-32)];
    }
    if (t < 32) bb[t] = b[t];
    size_t nb = (size_t)blockIdx.x * 128;
    const float4* xg = (const float4*)(x + nb * 64);
    for (int i = t; i < 128*16; i += 256) {
        int r = i >> 4, c = i & 15;
        *(float4*)(&xs[r*XPAD64 + c*4]) = xg[i];
    }
    __syncthreads();
    int q = t >> 5, ng = t & 31;
    float acc[4][8];
    #pragma unroll
    for (int i=0;i<4;++i)
        #pragma unroll
        for (int j=0;j<8;++j) acc[i][j]=0.f;
    #pragma unroll 4
    for (int k = 0; k < 64; k += 4) {
        float4 w0[4], w1[4];
        #pragma unroll
        for (int kk=0;kk<4;++kk) {
            w0[kk] = *(const float4*)(&wcat[(k+kk)*64 + q*8]);
            w1[kk] = *(const float4*)(&wcat[(k+kk)*64 + q*8 + 4]);
        }
        #pragma unroll
        for (int i=0;i<4;++i) {
            float4 xv = *(const float4*)(&xs[(ng + i*32)*XPAD64 + k]);
            float xvv[4] = {xv.x, xv.y, xv.z, xv.w};
            #pragma unroll
            for (int kk=0;kk<4;++kk) {
                acc[i][0]=fmaf(xvv[kk], w0[kk].x, acc[i][0]);
                acc[i][1]=fmaf(xvv[kk], w0[kk].y, acc[i][1]);
                acc[i][2]=fmaf(xvv[kk], w0[kk].z, acc[i][2]);
                acc[i][3]=fmaf(xvv[kk], w0[kk].w, acc[i][3]);
                acc[i][4]=fmaf(xvv[kk], w1[kk].x, acc[i][4]);
                acc[i][5]=fmaf(xvv[kk], w1[kk].y, acc[i][5]);
                acc[i][6]=fmaf(xvv[kk], w1[kk].z, acc[i][6]);
                acc[i][7]=fmaf(xvv[kk], w1[kk].w, acc[i][7]);
            }
        }
    }
    if (q < 4) {
        #pragma unroll
        for (int i=0;i<4;++i) {
            float* yr = y + (nb + ng + i*32)*32 + q*8;
            *(float4*)yr     = make_float4(acc[i][0],acc[i][1],acc[i][2],acc[i][3]);
            *(float4*)(yr+4) = make_float4(acc[i][4],acc[i][5],acc[i][6],acc[i][7]);
        }
    } else {
        int qq = q - 4;
        float b0=bb[qq*8+0],b1=bb[qq*8+1],b2=bb[qq*8+2],b3=bb[qq*8+3];
        float b4=bb[qq*8+4],b5=bb[qq*8+5],b6=bb[qq*8+6],b7=bb[qq*8+7];
        #pragma unroll
        for (int i=0;i<4;++i) {
            float* sr = seed + (nb + ng + i*32)*32 + qq*8;
            *(float4*)sr     = make_float4(acc[i][0]+b0,acc[i][1]+b1,acc[i][2]+b2,acc[i][3]+b3);
            *(float4*)(sr+4) = make_float4(acc[i][4]+b4,acc[i][5]+b5,acc[i][6]+b6,acc[i][7]+b7);
        }
    }
}

// ---------- conv2 front-end: same structure, K=32, ts folded as ts*(h@W) ----------
#define XPAD32 36
__global__ __launch_bounds__(256) void k_gemm32(
    const float* __restrict__ h, const float* __restrict__ ts,
    const float* __restrict__ Wrel, const float* __restrict__ Wroot,
    const float* __restrict__ b, float* __restrict__ y,
    float* __restrict__ seed)
{
    __shared__ float xs[128*XPAD32];
    __shared__ float wcat[32*64];
    __shared__ float bb[32];
    int t = threadIdx.x;
    for (int i = t; i < 32*64; i += 256) {
        int k = i >> 6, j = i & 63;
        wcat[i] = (j < 32) ? Wrel[k*32 + j] : Wroot[k*32 + (j-32)];
    }
    if (t < 32) bb[t] = b[t];
    size_t nb = (size_t)blockIdx.x * 128;
    const float4* hg = (const float4*)(h + nb * 32);
    for (int i = t; i < 128*8; i += 256) {
        int r = i >> 3, c = i & 7;
        *(float4*)(&xs[r*XPAD32 + c*4]) = hg[i];
    }
    __syncthreads();
    int q = t >> 5, ng = t & 31;
    float tsv[4];
    #pragma unroll
    for (int i=0;i<4;++i) tsv[i] = ts[nb + ng + i*32];
    float acc[4][8];
    #pragma unroll
    for (int i=0;i<4;++i)
        #pragma unroll
        for (int j=0;j<8;++j) acc[i][j]=0.f;
    #pragma unroll 4
    for (int k = 0; k < 32; k += 4) {
        float4 w0[4], w1[4];
        #pragma unroll
        for (int kk=0;kk<4;++kk) {
            w0[kk] = *(const float4*)(&wcat[(k+kk)*64 + q*8]);
            w1[kk] = *(const float4*)(&wcat[(k+kk)*64 + q*8 + 4]);
        }
        #pragma unroll
        for (int i=0;i<4;++i) {
            float4 xv = *(const float4*)(&xs[(ng + i*32)*XPAD32 + k]);
            float xvv[4] = {xv.x, xv.y, xv.z, xv.w};
            #pragma unroll
            for (int kk=0;kk<4;++kk) {
                acc[i][0]=fmaf(xvv[kk], w0[kk].x, acc[i][0]);
                acc[i][1]=fmaf(xvv[kk], w0[kk].y, acc[i][1]);
                acc[i][2]=fmaf(xvv[kk], w0[kk].z, acc[i][2]);
                acc[i][3]=fmaf(xvv[kk], w0[kk].w, acc[i][3]);
                acc[i][4]=fmaf(xvv[kk], w1[kk].x, acc[i][4]);
                acc[i][5]=fmaf(xvv[kk], w1[kk].y, acc[i][5]);
                acc[i][6]=fmaf(xvv[kk], w1[kk].z, acc[i][6]);
                acc[i][7]=fmaf(xvv[kk], w1[kk].w, acc[i][7]);
            }
        }
    }
    if (q < 4) {
        #pragma unroll
        for (int i=0;i<4;++i) {
            float sc = tsv[i];
            float* yr = y + (nb + ng + i*32)*32 + q*8;
            *(float4*)yr     = make_float4(acc[i][0]*sc,acc[i][1]*sc,acc[i][2]*sc,acc[i][3]*sc);
            *(float4*)(yr+4) = make_float4(acc[i][4]*sc,acc[i][5]*sc,acc[i][6]*sc,acc[i][7]*sc);
        }
    } else {
        int qq = q - 4;
        float b0=bb[qq*8+0],b1=bb[qq*8+1],b2=bb[qq*8+2],b3=bb[qq*8+3];
        float b4=bb[qq*8+4],b5=bb[qq*8+5],b6=bb[qq*8+6],b7=bb[qq*8+7];
        #pragma unroll
        for (int i=0;i<4;++i) {
            float sc = tsv[i];
            float* sr = seed + (nb + ng + i*32)*32 + qq*8;
            *(float4*)sr     = make_float4(acc[i][0]*sc+b0,acc[i][1]*sc+b1,acc[i][2]*sc+b2,acc[i][3]*sc+b3);
            *(float4*)(sr+4) = make_float4(acc[i][4]*sc+b4,acc[i][5]*sc+b5,acc[i][6]*sc+b6,acc[i][7]*sc+b7);
        }
    }
}

// ---------- fused gather + relu + score (walks 2 CSR segments) ----------
// XCD-aware block swizzle: each XCD owns a contiguous 1/8 of the grid
// (= 16 graphs = 4 MB of y-windows -> L2-resident on its own XCD).
__global__ __launch_bounds__(256) void k_gather(
    const int2* __restrict__ meta, const int2* __restrict__ edge_sorted,
    const float* __restrict__ y, const float* __restrict__ pw,
    const int* __restrict__ mask, const float* __restrict__ seedbuf,
    float* __restrict__ hout, float* __restrict__ s)
{
    unsigned orig = blockIdx.x;
    unsigned nwg8 = gridDim.x >> 3;              // grid divisible by 8
    unsigned bid = (orig & 7u) * nwg8 + (orig >> 3);
    size_t tid = (size_t)bid * 256 + threadIdx.x;
    int node = (int)(tid >> 3);
    int q = (int)(tid & 7);
    float4 wv = ((const float4*)pw)[q];
    float nn = wv.x*wv.x + wv.y*wv.y + wv.z*wv.z + wv.w*wv.w;
    nn += __shfl_xor(nn, 1); nn += __shfl_xor(nn, 2); nn += __shfl_xor(nn, 4);
    float nrm = sqrtf(nn);
    bool valid = mask ? (mask[node] != 0) : true;
    float4 acc = make_float4(0.f, 0.f, 0.f, 0.f);
    if (valid) {
        acc = *(const float4*)(seedbuf + (size_t)node * 32 + (size_t)q * 4);
        #pragma unroll
        for (int p = 0; p < 2; ++p) {
            int2 m = meta[(size_t)p*NNODES + node];
            int end = m.x + m.y;
            for (int e = m.x; e < end; ++e) {
                int2 ed = edge_sorted[e];
                float w = __int_as_float(ed.y);
                float4 v = *(const float4*)(y + (size_t)ed.x * 32 + (size_t)q * 4);
                acc.x = fmaf(v.x, w, acc.x);
                acc.y = fmaf(v.y, w, acc.y);
                acc.z = fmaf(v.z, w, acc.z);
                acc.w = fmaf(v.w, w, acc.w);
            }
        }
    }
    float4 hv;
    hv.x = fmaxf(acc.x, 0.f); hv.y = fmaxf(acc.y, 0.f);
    hv.z = fmaxf(acc.z, 0.f); hv.w = fmaxf(acc.w, 0.f);
    *(float4*)(hout + (size_t)node * 32 + (size_t)q * 4) = hv;
    float dot = hv.x*wv.x + hv.y*wv.y + hv.z*wv.z + hv.w*wv.w;
    dot += __shfl_xor(dot, 1); dot += __shfl_xor(dot, 2); dot += __shfl_xor(dot, 4);
    if (q == 0) s[node] = valid ? (dot / nrm) : -INFINITY;
}

// ---------- pooling: 1024-thread radix select + reduce ----------
__global__ __launch_bounds__(1024) void k_pool(
    const float* __restrict__ s, const float* __restrict__ h,
    float* __restrict__ ts_out, int* __restrict__ mask_out,
    float* __restrict__ xout, int ksel)
{
    __shared__ unsigned keys[NPG];
    __shared__ unsigned hist[256];
    __shared__ unsigned scanb[256];
    __shared__ unsigned tiescan[1024];
    __shared__ unsigned char flag[NPG];
    __shared__ unsigned sh_bin, sh_krem;
    __shared__ float red[16*64];
    int t = threadIdx.x;
    int g = blockIdx.x;
    const float* sg = s + (size_t)g * NPG;
    for (int i = t; i < NPG; i += 1024) {
        unsigned u = __float_as_uint(sg[i]);
        keys[i] = (u & 0x80000000u) ? ~u : (u | 0x80000000u);
    }
    __syncthreads();
    unsigned prefix = 0u;
    unsigned krem = (unsigned)ksel;
    for (int level = 0; level < 4; ++level) {
        int shift = 24 - 8*level;
        if (t < 256) hist[t] = 0u;
        __syncthreads();
        unsigned pmask = level ? (0xFFFFFFFFu << (shift + 8)) : 0u;
        for (int i = t; i < NPG; i += 1024) {
            unsigned key = keys[i];
            if ((key & pmask) == prefix)
                atomicAdd(&hist[(key >> shift) & 0xFFu], 1u);
        }
        __syncthreads();
        if (t < 256) scanb[t] = hist[255 - t];
        __syncthreads();
        for (int off = 1; off < 256; off <<= 1) {
            unsigned add = (t < 256 && t >= off) ? scanb[t - off] : 0u;
            __syncthreads();
            if (t < 256) scanb[t] += add;
            __syncthreads();
        }
        if (t < 256) {
            unsigned incl = scanb[t];
            unsigned excl = t ? scanb[t-1] : 0u;
            if (incl >= krem && excl < krem) {
                sh_bin = (unsigned)(255 - t);
                sh_krem = krem - excl;
            }
        }
        __syncthreads();
        prefix |= (sh_bin << shift);
        krem = sh_krem;
        __syncthreads();
    }
    unsigned T = prefix;
    unsigned ties = krem;
    int base = t * 2;
    unsigned k0 = keys[base], k1 = keys[base+1];
    unsigned ceq = (k0 == T ? 1u : 0u) + (k1 == T ? 1u : 0u);
    tiescan[t] = ceq;
    __syncthreads();
    for (int off = 1; off < 1024; off <<= 1) {
        unsigned add = (t >= off) ? tiescan[t - off] : 0u;
        __syncthreads();
        tiescan[t] += add;
        __syncthreads();
    }
    unsigned run = tiescan[t] - ceq;
    {
        unsigned char f0, f1;
        if (k0 > T) f0 = 1;
        else if (k0 == T) { f0 = (run < ties) ? 1 : 0; run++; }
        else f0 = 0;
        if (k1 > T) f1 = 1;
        else if (k1 == T) { f1 = (run < ties) ? 1 : 0; run++; }
        else f1 = 0;
        flag[base] = f0; flag[base+1] = f1;
    }
    __syncthreads();

    float mx[32], sm[32];
    #pragma unroll
    for (int j=0;j<32;++j){ mx[j]=-INFINITY; sm[j]=0.f; }
    const float* hg = h + (size_t)g * NPG * 32;
    for (int i = t; i < NPG; i += 1024) {
        bool sel = flag[i] != 0;
        float tsv = sel ? tanhf(sg[i]) : 0.f;
        const float4* hr = (const float4*)(hg + (size_t)i*32);
        #pragma unroll
        for (int j4=0;j4<8;++j4) {
            float4 hv = hr[j4];
            float4 v = make_float4(hv.x*tsv, hv.y*tsv, hv.z*tsv, hv.w*tsv);
            if (sel) {
                mx[4*j4+0] = fmaxf(mx[4*j4+0], v.x); sm[4*j4+0] += v.x;
                mx[4*j4+1] = fmaxf(mx[4*j4+1], v.y); sm[4*j4+1] += v.y;
                mx[4*j4+2] = fmaxf(mx[4*j4+2], v.z); sm[4*j4+2] += v.z;
                mx[4*j4+3] = fmaxf(mx[4*j4+3], v.w); sm[4*j4+3] += v.w;
            }
        }
        if (ts_out) ts_out[(size_t)g*NPG + i] = tsv;
        if (mask_out) mask_out[(size_t)g*NPG + i] = sel ? 1 : 0;
    }
    #pragma unroll
    for (int j=0;j<32;++j) {
        for (int off=32; off; off>>=1) {
            mx[j] = fmaxf(mx[j], __shfl_xor(mx[j], off));
            sm[j] += __shfl_xor(sm[j], off);
        }
    }
    int wave = t >> 6, lane = t & 63;
    if (lane == 0) {
        #pragma unroll
        for (int j=0;j<32;++j) { red[wave*64 + j] = mx[j]; red[wave*64 + 32 + j] = sm[j]; }
    }
    __syncthreads();
    if (t < 32) {
        float m = red[t], ss = red[32 + t];
        #pragma unroll
        for (int w=1; w<16; ++w) { m = fmaxf(m, red[w*64 + t]); ss += red[w*64 + 32 + t]; }
        xout[(size_t)g*64 + t] = m;
        xout[(size_t)g*64 + 32 + t] = ss / (float)ksel;
    }
}

__global__ __launch_bounds__(128) void k_readout(
    const float* __restrict__ x1, const float* __restrict__ x2,
    const float* __restrict__ l1W, const float* __restrict__ l1b,
    const float* __restrict__ l2W, const float* __restrict__ l2b,
    const float* __restrict__ l3W, const float* __restrict__ l3b,
    float* __restrict__ out)
{
    int g = threadIdx.x;
    float z[64];
    #pragma unroll
    for (int i=0;i<64;++i) z[i] = x1[g*64+i] + x2[g*64+i];
    float a1[32];
    for (int j=0;j<32;++j) {
        float acc = l1b[j];
        #pragma unroll
        for (int i=0;i<64;++i) acc = fmaf(z[i], l1W[i*32+j], acc);
        a1[j] = fmaxf(acc, 0.f);
    }
    float a2[16];
    for (int j=0;j<16;++j) {
        float acc = l2b[j];
        #pragma unroll
        for (int i=0;i<32;++i) acc = fmaf(a1[i], l2W[i*16+j], acc);
        a2[j] = fmaxf(acc, 0.f);
    }
    float o0 = l3b[0], o1 = l3b[1];
    #pragma unroll
    for (int i=0;i<16;++i) { o0 = fmaf(a2[i], l3W[i*2+0], o0); o1 = fmaf(a2[i], l3W[i*2+1], o1); }
    float m = fmaxf(o0, o1);
    float lse = m + logf(expf(o0-m) + expf(o1-m));
    out[g*2+0] = o0 - lse;
    out[g*2+1] = o1 - lse;
}

extern "C" void kernel_launch(void* const* d_in, const int* in_sizes, int n_in,
                              void* d_out, int out_size, void* d_ws, size_t ws_size,
                              hipStream_t stream)
{
    const float* x      = (const float*)d_in[0];
    const int*   ei     = (const int*)d_in[1];   // int32 (JAX x64 disabled)
    const float* eattr  = (const float*)d_in[2];
    const float* W1rel  = (const float*)d_in[4];
    const float* b1     = (const float*)d_in[5];
    const float* W1root = (const float*)d_in[6];
    const float* p1w    = (const float*)d_in[7];
    const float* W2rel  = (const float*)d_in[8];
    const float* b2     = (const float*)d_in[9];
    const float* W2root = (const float*)d_in[10];
    const float* p2w    = (const float*)d_in[11];
    const float* l1W    = (const float*)d_in[12];
    const float* l1b    = (const float*)d_in[13];
    const float* l2W    = (const float*)d_in[14];
    const float* l2b    = (const float*)d_in[15];
    const float* l3W    = (const float*)d_in[16];
    const float* l3b    = (const float*)d_in[17];
    const int* srcp = ei;
    const int* dstp = ei + NEDGES;

    float* ws   = (float*)d_ws;
    float* y    = ws;                                 // [NNODES,32]
    float* aggh = y    + (size_t)NNODES*32;           // [NNODES,32] h
    float* seedb= aggh + (size_t)NNODES*32;           // [NNODES,32] seed
    float* s1   = seedb+ (size_t)NNODES*32;           // [NNODES]
    float* ts   = s1 + NNODES;                        // [NNODES]
    int*   mask = (int*)(ts + NNODES);                // [NNODES]
    float* x1   = (float*)(mask + NNODES);            // [128,64]
    float* x2   = x1 + NGRAPH*64;                     // [128,64]
    int2*  meta = (int2*)(x2 + NGRAPH*64);            // [2*NNODES] (start,count)
    int2*  edge_sorted = (int2*)(meta + 2*NNODES);    // [NEDGES] (src, ew)
    float* out  = (float*)d_out;

    dim3 b256(256);
    // ---- partitioned CSR: 2 WGs per graph ----
    k_csr<<<NGRAPH*2, dim3(1024), 0, stream>>>(srcp, dstp, eattr, meta,
                                               edge_sorted);
    // ---- conv1 front-end + gather/score (XCD-swizzled) ----
    k_gemm64<<<NNODES/128, b256, 0, stream>>>(x, W1rel, W1root, b1, y, seedb);
    k_gather<<<NNODES*8/256, b256, 0, stream>>>(meta, edge_sorted,
                                                y, p1w, nullptr, seedb, aggh, s1);
    // ---- pool1 (ts + mask + x1; h untouched) ----
    k_pool<<<NGRAPH, dim3(1024), 0, stream>>>(s1, aggh, ts, mask, x1, KSEL1);
    // ---- conv2 front-end (ts fused) + gather/score (XCD-swizzled) ----
    k_gemm32<<<NNODES/128, b256, 0, stream>>>(aggh, ts, W2rel, W2root, b2, y, seedb);
    k_gather<<<NNODES*8/256, b256, 0, stream>>>(meta, edge_sorted,
                                                y, p2w, mask, seedb, aggh, s1);
    // ---- pool2 (x2 only) ----
    k_pool<<<NGRAPH, dim3(1024), 0, stream>>>(s1, aggh, nullptr, nullptr, x2, KSEL2);
    // ---- readout MLP ----
    k_readout<<<1, 128, 0, stream>>>(x1, x2, l1W, l1b, l2W, l2b, l3W, l3b, out);
}